// Round 11
// baseline (130.190 us; speedup 1.0000x reference)
//
#include <hip/hip_runtime.h>
#include <hip/hip_cooperative_groups.h>
#include <hip/hip_bf16.h>

namespace cg = cooperative_groups;

// Problem: B=24, L=512, D=64, H=64
//   h = gelu(x @ W + b); S = h_i h_j^T per pair; scores = logsumexp(S).
// scores = log(sum 2^(S*log2e)); B operand pre-scaled by log2e. 300
// unique (i<=j) pairs, mirrored at the end.
//
// R11: cooperative fusion, conservative grid. R10's 1024-block launch was
// rejected (out==0, fast return -> hipErrorCooperativeLaunchTooLarge).
// 512 blocks needs only 2 blocks/CU co-resident (safe to 256 VGPR; LDS
// allows 5/CU at 32KB). No min-waves launch-bounds cap. Phase1 encode
// (waves 0-1, units u=wid*512+blk) -> grid.sync -> Phase2 persistent
// 1200 pair-tiles (R8 loop) -> grid.sync -> Phase3 log+mirror.

#define LOG2E 1.4426950408889634f

typedef unsigned short u16;
typedef __attribute__((ext_vector_type(8))) short bf16x8;
typedef __attribute__((ext_vector_type(4))) float f32x4;

static __device__ __forceinline__ u16 bf16bits(float f) {
  __hip_bfloat16 h = __float2bfloat16(f);
  return *reinterpret_cast<u16*>(&h);
}

// Schraudolph fast 2^x: valid for x in (-126, 128), rel err <= 3.04%.
static __device__ __forceinline__ float fast_exp2(float x) {
  int i = (int)fmaf(x, 8388608.0f, 1065098601.0f);
  return __int_as_float(i);
}

__global__ __launch_bounds__(256) void fused_kernel(
    const float* __restrict__ x, const float* __restrict__ W,
    const float* __restrict__ bias, u16* __restrict__ hb,
    u16* __restrict__ hlb, float* __restrict__ part,
    float* __restrict__ out) {
  cg::grid_group grid = cg::this_grid();
  __shared__ char smem[32768];

  int lane = threadIdx.x & 63;
  int wid = threadIdx.x >> 6;
  int r = lane & 15;        // row-in-fragment
  int kg = lane >> 4;       // k-group (8 contiguous bf16 = 16B)

  // ---------------- Phase 1: encode h = gelu(x@W+b) via MFMA --------------
  // 768 units of 16 rows; unit u = wid*512 + blockIdx.x for wid<2.
  int u = wid * 512 + blockIdx.x;
  if (wid < 2 && u < 768) {
    int row0 = u * 16;

    bf16x8 xa[2];
#pragma unroll
    for (int kh = 0; kh < 2; ++kh) {
      const float* xp = x + (size_t)(row0 + r) * 64 + kh * 32 + kg * 8;
      bf16x8 v;
#pragma unroll
      for (int e = 0; e < 8; ++e) v[e] = (short)bf16bits(xp[e]);
      xa[kh] = v;
    }

    bf16x8 wf[4][2];
#pragma unroll
    for (int nb = 0; nb < 4; ++nb)
#pragma unroll
      for (int kh = 0; kh < 2; ++kh) {
        bf16x8 v;
#pragma unroll
        for (int e = 0; e < 8; ++e)
          v[e] = (short)bf16bits(W[(kh * 32 + kg * 8 + e) * 64 + nb * 16 + r]);
        wf[nb][kh] = v;
      }

    const f32x4 zero = {0.f, 0.f, 0.f, 0.f};
#pragma unroll
    for (int nb = 0; nb < 4; ++nb) {
      f32x4 acc = __builtin_amdgcn_mfma_f32_16x16x32_bf16(xa[0], wf[nb][0], zero, 0, 0, 0);
      acc = __builtin_amdgcn_mfma_f32_16x16x32_bf16(xa[1], wf[nb][1], acc, 0, 0, 0);
      float bb = bias[nb * 16 + r];
#pragma unroll
      for (int q = 0; q < 4; ++q) {
        float z = acc[q] + bb;
        // JAX default gelu (approximate=True, tanh form)
        float t = tanhf(0.7978845608028654f * (z + 0.044715f * z * z * z));
        float g = 0.5f * z * (1.0f + t);
        size_t o = (size_t)(row0 + kg * 4 + q) * 64 + nb * 16 + r;
        hb[o] = bf16bits(g);
        hlb[o] = bf16bits(g * LOG2E);
      }
    }
  }

  grid.sync();

  // ---------------- Phase 2: pair tiles (persistent loop) -----------------
  // tile t of 1200 = 300 pairs x (2 row-halves x 2 col-halves).
  for (int t = blockIdx.x; t < 1200; t += gridDim.x) {
    __syncthreads();  // LDS reuse across loop iterations

    int p = t >> 2;
    int tile = t & 3;
    int rh = tile >> 1;
    int ch = tile & 1;
    // decode triangular index p -> (i,j), i<=j
    int i = 0, rem = p;
    while (rem >= 24 - i) { rem -= 24 - i; ++i; }
    int j = i + rem;

    const u16* Ap = hb + (size_t)i * 512 * 64;
    const char* Bbytes =
        (const char*)(hlb + (size_t)j * 512 * 64) + (size_t)ch * 256 * 128;
    int row0 = rh * 256 + wid * 64;

    // A fragments: 64 rows, K=64 (4 rm x 2 k-halves).
    bf16x8 a[4][2];
#pragma unroll
    for (int rm = 0; rm < 4; ++rm)
#pragma unroll
      for (int kf = 0; kf < 2; ++kf)
        a[rm][kf] = *reinterpret_cast<const bf16x8*>(
            Ap + (size_t)(row0 + rm * 16 + r) * 64 + kf * 32 + kg * 8);

    // Stage B half (32KB), XOR-swizzled via pre-swizzled global source.
#pragma unroll
    for (int c = 0; c < 8; ++c) {
      int obase = (wid * 8 + c) * 1024;
      int o = obase + lane * 16;
      int src = o ^ (((o >> 7) & 7) << 4);
      __builtin_amdgcn_global_load_lds(
          (const __attribute__((address_space(1))) void*)(Bbytes + src),
          (__attribute__((address_space(3))) void*)(smem + obase), 16, 0, 0);
    }

    int sw = (r & 7) << 4;
    int off0 = r * 128 + ((kg * 16) ^ sw);
    int off1 = r * 128 + ((64 + kg * 16) ^ sw);

    __syncthreads();

    float s0 = 0.f, s1 = 0.f, s2 = 0.f, s3 = 0.f;
    const f32x4 zero = {0.f, 0.f, 0.f, 0.f};

#pragma unroll
    for (int cn = 0; cn < 16; ++cn) {
      const char* bp = smem + cn * 2048;
      bf16x8 b0 = *reinterpret_cast<const bf16x8*>(bp + off0);
      bf16x8 b1 = *reinterpret_cast<const bf16x8*>(bp + off1);
#pragma unroll
      for (int rm = 0; rm < 4; ++rm) {
        f32x4 acc = __builtin_amdgcn_mfma_f32_16x16x32_bf16(a[rm][0], b0, zero, 0, 0, 0);
        acc = __builtin_amdgcn_mfma_f32_16x16x32_bf16(a[rm][1], b1, acc, 0, 0, 0);
        s0 += fast_exp2(acc[0]);
        s1 += fast_exp2(acc[1]);
        s2 += fast_exp2(acc[2]);
        s3 += fast_exp2(acc[3]);
      }
    }
    float sum = (s0 + s1) + (s2 + s3);
#pragma unroll
    for (int off = 32; off >= 1; off >>= 1) sum += __shfl_xor(sum, off, 64);
    if (lane == 0) part[t * 4 + wid] = sum;
  }

  grid.sync();

  // ---------------- Phase 3: sum 16 partials per pair, log, mirror --------
  int tid = blockIdx.x * blockDim.x + threadIdx.x;
  if (tid < 576) {
    int oi = tid / 24, oj = tid % 24;
    int ii = oi < oj ? oi : oj, jj = oi < oj ? oj : oi;
    int p = ii * 24 - ii * (ii - 1) / 2 + (jj - ii);
    const f32x4* pv = reinterpret_cast<const f32x4*>(part + p * 16);
    float s = 0.f;
#pragma unroll
    for (int q = 0; q < 4; ++q) {
      f32x4 v = pv[q];
      s += (v[0] + v[1]) + (v[2] + v[3]);
    }
    out[tid] = logf(s);
  }
}

extern "C" void kernel_launch(void* const* d_in, const int* in_sizes, int n_in,
                              void* d_out, int out_size, void* d_ws,
                              size_t ws_size, hipStream_t stream) {
  const float* x = (const float*)d_in[0];
  const float* W = (const float*)d_in[1];
  const float* bias = (const float*)d_in[2];
  float* out = (float*)d_out;

  u16* hb = (u16*)d_ws;                      // 12288*64 bf16 = 1.50 MiB
  u16* hlb = hb + 12288 * 64;                // 1.50 MiB
  float* part = (float*)(hlb + 12288 * 64);  // 1200 * 4 = 4800 f32

  void* args[] = {(void*)&x, (void*)&W, (void*)&bias, (void*)&hb,
                  (void*)&hlb, (void*)&part, (void*)&out};
  hipLaunchCooperativeKernel((void*)fused_kernel, dim3(512), dim3(256),
                             args, 0, stream);
}

// Round 12
// 45.888 us; speedup vs baseline: 2.8371x; 2.8371x over previous
//
#include <hip/hip_runtime.h>
#include <hip/hip_bf16.h>

// Problem: B=24, L=512, D=64, H=64
//   h = gelu(x @ W + b); S = h_i h_j^T per pair; scores = logsumexp(S).
// scores = log(sum 2^(S*log2e)); B operand pre-scaled by log2e. 300
// unique (i<=j) pairs, mirrored at the end.
//
// R12 (base = R8, 27.9us): (1) depth-2 software pipeline: MFMA(cn+1)
// issued into pN[] BEFORE exp-consuming pA[] of cn — hides MFMA->VALU
// result latency (the invariant ~1000cyc/cn stall across R4-R8 variants).
// (2) finish fused into pair: atomicAdd sums + done-counter; last block
// of each pair writes both mirror cells (3->2 dispatches). (3) encode as
// 768 x 64thr blocks (3/CU; was 0.75/CU).

#define LOG2E 1.4426950408889634f

typedef unsigned short u16;
typedef unsigned int u32;
typedef __attribute__((ext_vector_type(8))) short bf16x8;
typedef __attribute__((ext_vector_type(4))) float f32x4;

static __device__ __forceinline__ u16 bf16bits(float f) {
  __hip_bfloat16 h = __float2bfloat16(f);
  return *reinterpret_cast<u16*>(&h);
}

// Schraudolph fast 2^x: valid for x in (-126, 128), rel err <= 3.04%.
static __device__ __forceinline__ float fast_exp2(float x) {
  int i = (int)fmaf(x, 8388608.0f, 1065098601.0f);
  return __int_as_float(i);
}

// ---------------- encoder: h = gelu(x@W+b) via MFMA -----------------------
// 768 blocks x 64 thr; block = one 16-row unit. Blocks 0-9 also zero
// the sums/cnt scratch (600 u32) — stream-ordered before pair.
__global__ __launch_bounds__(64) void encode_kernel(
    const float* __restrict__ x, const float* __restrict__ W,
    const float* __restrict__ bias, u16* __restrict__ hb,
    u16* __restrict__ hlb, u32* __restrict__ sums_cnt) {
  int lane = threadIdx.x;
  if (blockIdx.x < 10) {
    int t = blockIdx.x * 64 + lane;
    if (t < 600) sums_cnt[t] = 0u;
  }

  int row0 = blockIdx.x * 16;
  int r = lane & 15;
  int kg = lane >> 4;

  bf16x8 xa[2];
#pragma unroll
  for (int kh = 0; kh < 2; ++kh) {
    const float* xp = x + (size_t)(row0 + r) * 64 + kh * 32 + kg * 8;
    bf16x8 v;
#pragma unroll
    for (int e = 0; e < 8; ++e) v[e] = (short)bf16bits(xp[e]);
    xa[kh] = v;
  }

  bf16x8 wf[4][2];
#pragma unroll
  for (int nb = 0; nb < 4; ++nb)
#pragma unroll
    for (int kh = 0; kh < 2; ++kh) {
      bf16x8 v;
#pragma unroll
      for (int e = 0; e < 8; ++e)
        v[e] = (short)bf16bits(W[(kh * 32 + kg * 8 + e) * 64 + nb * 16 + r]);
      wf[nb][kh] = v;
    }

  const f32x4 zero = {0.f, 0.f, 0.f, 0.f};
#pragma unroll
  for (int nb = 0; nb < 4; ++nb) {
    f32x4 acc = __builtin_amdgcn_mfma_f32_16x16x32_bf16(xa[0], wf[nb][0], zero, 0, 0, 0);
    acc = __builtin_amdgcn_mfma_f32_16x16x32_bf16(xa[1], wf[nb][1], acc, 0, 0, 0);
    float bb = bias[nb * 16 + r];
#pragma unroll
    for (int q = 0; q < 4; ++q) {
      float z = acc[q] + bb;
      // JAX default gelu (approximate=True, tanh form)
      float t = tanhf(0.7978845608028654f * (z + 0.044715f * z * z * z));
      float g = 0.5f * z * (1.0f + t);
      size_t o = (size_t)(row0 + kg * 4 + q) * 64 + nb * 16 + r;
      hb[o] = bf16bits(g);
      hlb[o] = bf16bits(g * LOG2E);
    }
  }
}

// ---------------- pair kernel (finish fused) -------------------------------
// 1200 blocks = 300 pairs x (2 row-halves x 2 col-halves). Block =
// 256 A-rows x 256 B-rows; B half (32KB) staged once to LDS (swizzled).
// Wave = 64 A-rows x 256 cols, depth-2 acc pipeline. Block sum ->
// atomicAdd(sums[p]); 4th finisher computes log and writes out (mirror).
__global__ __launch_bounds__(256) void pair_kernel(
    const u16* __restrict__ hb, const u16* __restrict__ hlb,
    u32* __restrict__ sums_cnt, float* __restrict__ out) {
  __shared__ char smem[32768];

  float* sums = (float*)sums_cnt;        // [300]
  u32* cnt = sums_cnt + 300;             // [300]

  int idx = blockIdx.x;
  int p = idx >> 2;
  int tile = idx & 3;
  int rh = tile >> 1;          // row half of A (256 rows)
  int ch = tile & 1;           // col half of B (256 rows)
  // decode triangular index p -> (i,j), i<=j
  int i = 0, rem = p;
  while (rem >= 24 - i) { rem -= 24 - i; ++i; }
  int j = i + rem;

  const u16* Ap = hb + (size_t)i * 512 * 64;
  const char* Bbytes =
      (const char*)(hlb + (size_t)j * 512 * 64) + (size_t)ch * 256 * 128;

  int wid = threadIdx.x >> 6;
  int lane = threadIdx.x & 63;
  int r = lane & 15;        // row-in-fragment
  int kg = lane >> 4;       // k-group (8 contiguous bf16 = 16B)
  int row0 = rh * 256 + wid * 64;

  // A fragments: 64 rows, K=64 (4 rm x 2 k-halves) — one-time L2 loads.
  bf16x8 a[4][2];
#pragma unroll
  for (int rm = 0; rm < 4; ++rm)
#pragma unroll
    for (int kf = 0; kf < 2; ++kf)
      a[rm][kf] = *reinterpret_cast<const bf16x8*>(
          Ap + (size_t)(row0 + rm * 16 + r) * 64 + kf * 32 + kg * 8);

  // Stage B half: 32KB. LDS dest linear; global source pre-swizzled with
  // the involution the reads use.
#pragma unroll
  for (int c = 0; c < 8; ++c) {
    int obase = (wid * 8 + c) * 1024;
    int o = obase + lane * 16;
    int src = o ^ (((o >> 7) & 7) << 4);
    __builtin_amdgcn_global_load_lds(
        (const __attribute__((address_space(1))) void*)(Bbytes + src),
        (__attribute__((address_space(3))) void*)(smem + obase), 16, 0, 0);
  }

  // Per-lane LDS read offsets (swizzle bits depend only on lane).
  int sw = (r & 7) << 4;
  int off0 = r * 128 + ((kg * 16) ^ sw);
  int off1 = r * 128 + ((64 + kg * 16) ^ sw);

  __syncthreads();

  const f32x4 zero = {0.f, 0.f, 0.f, 0.f};
  f32x4 s[2] = {zero, zero};   // 8 accumulators (rm&1 interleave)

  // ---- depth-2 pipeline: MFMA for cn+1 in flight while exp-consuming cn.
  f32x4 pA[4], pN[4];
  {
    bf16x8 b0 = *reinterpret_cast<const bf16x8*>(smem + off0);
    bf16x8 b1 = *reinterpret_cast<const bf16x8*>(smem + off1);
#pragma unroll
    for (int rm = 0; rm < 4; ++rm) {
      pA[rm] = __builtin_amdgcn_mfma_f32_16x16x32_bf16(a[rm][0], b0, zero, 0, 0, 0);
      pA[rm] = __builtin_amdgcn_mfma_f32_16x16x32_bf16(a[rm][1], b1, pA[rm], 0, 0, 0);
    }
  }
#pragma unroll
  for (int cn = 1; cn <= 16; ++cn) {
    if (cn < 16) {
      const char* bp = smem + cn * 2048;
      bf16x8 b0 = *reinterpret_cast<const bf16x8*>(bp + off0);
      bf16x8 b1 = *reinterpret_cast<const bf16x8*>(bp + off1);
#pragma unroll
      for (int rm = 0; rm < 4; ++rm) {
        pN[rm] = __builtin_amdgcn_mfma_f32_16x16x32_bf16(a[rm][0], b0, zero, 0, 0, 0);
        pN[rm] = __builtin_amdgcn_mfma_f32_16x16x32_bf16(a[rm][1], b1, pN[rm], 0, 0, 0);
      }
    }
    // consume previous tile's acc while new MFMAs are in flight
#pragma unroll
    for (int rm = 0; rm < 4; ++rm) {
#pragma unroll
      for (int q = 0; q < 4; ++q) s[rm & 1][q] += fast_exp2(pA[rm][q]);
    }
    if (cn < 16) {
#pragma unroll
      for (int rm = 0; rm < 4; ++rm) pA[rm] = pN[rm];
    }
  }

  f32x4 sv = s[0] + s[1];
  float sum = (sv[0] + sv[1]) + (sv[2] + sv[3]);
#pragma unroll
  for (int off = 32; off >= 1; off >>= 1) sum += __shfl_xor(sum, off, 64);

  // Block reduction via LDS (alias smem AFTER all B reads are done).
  __syncthreads();
  if (lane == 0) *reinterpret_cast<float*>(smem + wid * 4) = sum;
  __syncthreads();

  if (threadIdx.x == 0) {
    const float* sf = reinterpret_cast<const float*>(smem);
    float bsum = (sf[0] + sf[1]) + (sf[2] + sf[3]);
    atomicAdd(&sums[p], bsum);
    __threadfence();   // sums-add visible before cnt-add
    u32 n = atomicAdd(&cnt[p], 1u);
    if (n == 3u) {
      // all 4 blocks' sums-adds precede their cnt-adds (fence), which
      // precede our observation; RMW-read gets the complete total.
      float total = atomicAdd(&sums[p], 0.0f);
      float sc = logf(total);
      out[i * 24 + j] = sc;
      if (i != j) out[j * 24 + i] = sc;
    }
  }
}

extern "C" void kernel_launch(void* const* d_in, const int* in_sizes, int n_in,
                              void* d_out, int out_size, void* d_ws,
                              size_t ws_size, hipStream_t stream) {
  const float* x = (const float*)d_in[0];
  const float* W = (const float*)d_in[1];
  const float* bias = (const float*)d_in[2];
  float* out = (float*)d_out;

  u16* hb = (u16*)d_ws;                      // 12288*64 bf16 = 1.50 MiB
  u16* hlb = hb + 12288 * 64;                // 1.50 MiB
  u32* sums_cnt = (u32*)(hlb + 12288 * 64);  // 300 f32 sums + 300 u32 cnt

  encode_kernel<<<768, 64, 0, stream>>>(x, W, bias, hb, hlb, sums_cnt);
  pair_kernel<<<1200, 256, 0, stream>>>(hb, hlb, sums_cnt, out);
}

// Round 13
// 42.831 us; speedup vs baseline: 3.0396x; 1.0714x over previous
//
#include <hip/hip_runtime.h>
#include <hip/hip_bf16.h>

// Problem: B=24, L=512, D=64, H=64
//   h = gelu(x @ W + b); S = h_i h_j^T per pair; scores = logsumexp(S).
// scores = log(sum 2^(S*log2e)); B operand pre-scaled by log2e. 300
// unique (i<=j) pairs, mirrored at the end.
//
// R13: R8's pair inner loop EXACTLY (compiler-scheduled, VGPR 44,
// 5 blocks/CU, 1200 blocks = one residency round) — R12's depth-2
// pipeline is reverted (it cost VGPR 44->100, occupancy 40->12%,
// pair 13->40us). Kept from R12: fused finisher (atomicAdd sums +
// done-counter; last block logs + writes both mirror cells) -> 2
// dispatches, and the 768x64 spread encoder which also zeroes scratch.

#define LOG2E 1.4426950408889634f

typedef unsigned short u16;
typedef unsigned int u32;
typedef __attribute__((ext_vector_type(8))) short bf16x8;
typedef __attribute__((ext_vector_type(4))) float f32x4;

static __device__ __forceinline__ u16 bf16bits(float f) {
  __hip_bfloat16 h = __float2bfloat16(f);
  return *reinterpret_cast<u16*>(&h);
}

// Schraudolph fast 2^x: valid for x in (-126, 128), rel err <= 3.04%.
static __device__ __forceinline__ float fast_exp2(float x) {
  int i = (int)fmaf(x, 8388608.0f, 1065098601.0f);
  return __int_as_float(i);
}

// ---------------- encoder: h = gelu(x@W+b) via MFMA -----------------------
// 768 blocks x 64 thr; block = one 16-row unit. Blocks 0-9 also zero
// the sums/cnt scratch (600 u32) — stream-ordered before pair.
__global__ __launch_bounds__(64) void encode_kernel(
    const float* __restrict__ x, const float* __restrict__ W,
    const float* __restrict__ bias, u16* __restrict__ hb,
    u16* __restrict__ hlb, u32* __restrict__ sums_cnt) {
  int lane = threadIdx.x;
  if (blockIdx.x < 10) {
    int t = blockIdx.x * 64 + lane;
    if (t < 600) sums_cnt[t] = 0u;
  }

  int row0 = blockIdx.x * 16;
  int r = lane & 15;
  int kg = lane >> 4;

  bf16x8 xa[2];
#pragma unroll
  for (int kh = 0; kh < 2; ++kh) {
    const float* xp = x + (size_t)(row0 + r) * 64 + kh * 32 + kg * 8;
    bf16x8 v;
#pragma unroll
    for (int e = 0; e < 8; ++e) v[e] = (short)bf16bits(xp[e]);
    xa[kh] = v;
  }

  bf16x8 wf[4][2];
#pragma unroll
  for (int nb = 0; nb < 4; ++nb)
#pragma unroll
    for (int kh = 0; kh < 2; ++kh) {
      bf16x8 v;
#pragma unroll
      for (int e = 0; e < 8; ++e)
        v[e] = (short)bf16bits(W[(kh * 32 + kg * 8 + e) * 64 + nb * 16 + r]);
      wf[nb][kh] = v;
    }

  const f32x4 zero = {0.f, 0.f, 0.f, 0.f};
#pragma unroll
  for (int nb = 0; nb < 4; ++nb) {
    f32x4 acc = __builtin_amdgcn_mfma_f32_16x16x32_bf16(xa[0], wf[nb][0], zero, 0, 0, 0);
    acc = __builtin_amdgcn_mfma_f32_16x16x32_bf16(xa[1], wf[nb][1], acc, 0, 0, 0);
    float bb = bias[nb * 16 + r];
#pragma unroll
    for (int q = 0; q < 4; ++q) {
      float z = acc[q] + bb;
      // JAX default gelu (approximate=True, tanh form)
      float t = tanhf(0.7978845608028654f * (z + 0.044715f * z * z * z));
      float g = 0.5f * z * (1.0f + t);
      size_t o = (size_t)(row0 + kg * 4 + q) * 64 + nb * 16 + r;
      hb[o] = bf16bits(g);
      hlb[o] = bf16bits(g * LOG2E);
    }
  }
}

// ---------------- pair kernel (R8 body + fused finish) ---------------------
// 1200 blocks = 300 pairs x (2 row-halves x 2 col-halves). Block =
// 256 A-rows x 256 B-rows; B half (32KB) staged once to LDS (swizzled).
// Wave = 64 A-rows x 256 cols. Block sum -> atomicAdd(sums[p]); the 4th
// finisher computes log and writes both mirror cells of out.
__global__ __launch_bounds__(256) void pair_kernel(
    const u16* __restrict__ hb, const u16* __restrict__ hlb,
    u32* __restrict__ sums_cnt, float* __restrict__ out) {
  __shared__ char smem[32768];

  float* sums = (float*)sums_cnt;        // [300]
  u32* cnt = sums_cnt + 300;             // [300]

  int idx = blockIdx.x;
  int p = idx >> 2;
  int tile = idx & 3;
  int rh = tile >> 1;          // row half of A (256 rows)
  int ch = tile & 1;           // col half of B (256 rows)
  // decode triangular index p -> (i,j), i<=j
  int i = 0, rem = p;
  while (rem >= 24 - i) { rem -= 24 - i; ++i; }
  int j = i + rem;

  const u16* Ap = hb + (size_t)i * 512 * 64;
  const char* Bbytes =
      (const char*)(hlb + (size_t)j * 512 * 64) + (size_t)ch * 256 * 128;

  int wid = threadIdx.x >> 6;
  int lane = threadIdx.x & 63;
  int r = lane & 15;        // row-in-fragment
  int kg = lane >> 4;       // k-group (8 contiguous bf16 = 16B)
  int row0 = rh * 256 + wid * 64;

  // A fragments: 64 rows, K=64 (4 rm x 2 k-halves) — one-time L2 loads.
  bf16x8 a[4][2];
#pragma unroll
  for (int rm = 0; rm < 4; ++rm)
#pragma unroll
    for (int kf = 0; kf < 2; ++kf)
      a[rm][kf] = *reinterpret_cast<const bf16x8*>(
          Ap + (size_t)(row0 + rm * 16 + r) * 64 + kf * 32 + kg * 8);

  // Stage B half: 32KB. LDS dest linear; global source pre-swizzled with
  // the involution the reads use.
#pragma unroll
  for (int c = 0; c < 8; ++c) {
    int obase = (wid * 8 + c) * 1024;
    int o = obase + lane * 16;
    int src = o ^ (((o >> 7) & 7) << 4);
    __builtin_amdgcn_global_load_lds(
        (const __attribute__((address_space(1))) void*)(Bbytes + src),
        (__attribute__((address_space(3))) void*)(smem + obase), 16, 0, 0);
  }

  // Per-lane LDS read offsets (swizzle bits depend only on lane).
  int sw = (r & 7) << 4;
  int off0 = r * 128 + ((kg * 16) ^ sw);
  int off1 = r * 128 + ((64 + kg * 16) ^ sw);

  __syncthreads();

  float s0 = 0.f, s1 = 0.f, s2 = 0.f, s3 = 0.f;
  const f32x4 zero = {0.f, 0.f, 0.f, 0.f};

#pragma unroll
  for (int cn = 0; cn < 16; ++cn) {
    const char* bp = smem + cn * 2048;
    bf16x8 b0 = *reinterpret_cast<const bf16x8*>(bp + off0);
    bf16x8 b1 = *reinterpret_cast<const bf16x8*>(bp + off1);
#pragma unroll
    for (int rm = 0; rm < 4; ++rm) {
      f32x4 acc = __builtin_amdgcn_mfma_f32_16x16x32_bf16(a[rm][0], b0, zero, 0, 0, 0);
      acc = __builtin_amdgcn_mfma_f32_16x16x32_bf16(a[rm][1], b1, acc, 0, 0, 0);
      s0 += fast_exp2(acc[0]);
      s1 += fast_exp2(acc[1]);
      s2 += fast_exp2(acc[2]);
      s3 += fast_exp2(acc[3]);
    }
  }
  float sum = (s0 + s1) + (s2 + s3);
#pragma unroll
  for (int off = 32; off >= 1; off >>= 1) sum += __shfl_xor(sum, off, 64);

  // Block reduction via LDS (alias smem AFTER all B reads are done).
  __syncthreads();
  if (lane == 0) *reinterpret_cast<float*>(smem + wid * 4) = sum;
  __syncthreads();

  if (threadIdx.x == 0) {
    const float* sf = reinterpret_cast<const float*>(smem);
    float bsum = (sf[0] + sf[1]) + (sf[2] + sf[3]);
    atomicAdd(&sums[p], bsum);
    __threadfence();   // sums-add visible before cnt-add
    u32 n = atomicAdd(&cnt[p], 1u);
    if (n == 3u) {
      // all 4 blocks' sums-adds precede their cnt-adds (fence), which
      // precede our observation; RMW-read gets the complete total.
      float total = atomicAdd(&sums[p], 0.0f);
      float sc = logf(total);
      out[i * 24 + j] = sc;
      if (i != j) out[j * 24 + i] = sc;
    }
  }
}

extern "C" void kernel_launch(void* const* d_in, const int* in_sizes, int n_in,
                              void* d_out, int out_size, void* d_ws,
                              size_t ws_size, hipStream_t stream) {
  const float* x = (const float*)d_in[0];
  const float* W = (const float*)d_in[1];
  const float* bias = (const float*)d_in[2];
  float* out = (float*)d_out;

  u16* hb = (u16*)d_ws;                      // 12288*64 bf16 = 1.50 MiB
  u16* hlb = hb + 12288 * 64;                // 1.50 MiB
  u32* sums_cnt = (u32*)(hlb + 12288 * 64);  // 300 f32 sums + 300 u32 cnt

  encode_kernel<<<768, 64, 0, stream>>>(x, W, bias, hb, hlb, sums_cnt);
  pair_kernel<<<1200, 256, 0, stream>>>(hb, hlb, sums_cnt, out);
}

// Round 14
// 26.214 us; speedup vs baseline: 4.9665x; 1.6339x over previous
//
#include <hip/hip_runtime.h>
#include <hip/hip_bf16.h>

// Problem: B=24, L=512, D=64, H=64
//   h = gelu(x @ W + b); S = h_i h_j^T per pair; scores = logsumexp(S).
// 300 unique (i<=j) pairs, mirrored at the end.
//
// R14 = R8 (best verified, 27.9us) + log2e folded into the Schraudolph
// constant: e^S ~= as_float((int)fmaf(S, 12102203, 1065098601)). This
// deletes the hlb (h*log2e) array entirely: encode writes one bf16 array,
// pair stages plain hb for both operands (h footprint 3->1.5MB, half the
// encode stores, one fewer bf16 rounding on B). R12/R13's atomic+fence
// finisher is reverted (threadfence = device L2 flush, +25us over 1200
// blocks). 3 dispatches, part[] slot writes, no atomics, no memset.

typedef unsigned short u16;
typedef __attribute__((ext_vector_type(8))) short bf16x8;
typedef __attribute__((ext_vector_type(4))) float f32x4;

static __device__ __forceinline__ u16 bf16bits(float f) {
  __hip_bfloat16 h = __float2bfloat16(f);
  return *reinterpret_cast<u16*>(&h);
}

// Schraudolph fast e^x (log2e folded into the multiplier):
// e^x ~= as_float((int)(x*log2e*2^23 + (127*2^23 - 254615))).
// Valid |x| < 87; rel err <= 3.04%  ->  <=0.03 absolute on log-scores.
static __device__ __forceinline__ float fast_exp(float x) {
  int i = (int)fmaf(x, 12102203.0f, 1065098601.0f);
  return __int_as_float(i);
}

// ---------------- encoder: h = gelu(x@W+b) via MFMA -----------------------
// Wave handles 16 rows. A = x rows (bf16), B = W (bf16). 8 MFMA/wave.
// D layout: col = lane&15, row_in_tile = (lane>>4)*4 + q.
__global__ __launch_bounds__(256) void encode_kernel(
    const float* __restrict__ x, const float* __restrict__ W,
    const float* __restrict__ bias, u16* __restrict__ hb) {
  int lane = threadIdx.x & 63;
  int wid = threadIdx.x >> 6;
  int row0 = (blockIdx.x * 4 + wid) * 16;      // 12288 rows / 16 = 768 waves
  int r = lane & 15;
  int kg = lane >> 4;

  bf16x8 xa[2];
#pragma unroll
  for (int kh = 0; kh < 2; ++kh) {
    const float* xp = x + (size_t)(row0 + r) * 64 + kh * 32 + kg * 8;
    bf16x8 v;
#pragma unroll
    for (int e = 0; e < 8; ++e) v[e] = (short)bf16bits(xp[e]);
    xa[kh] = v;
  }

  bf16x8 wf[4][2];
#pragma unroll
  for (int nb = 0; nb < 4; ++nb)
#pragma unroll
    for (int kh = 0; kh < 2; ++kh) {
      bf16x8 v;
#pragma unroll
      for (int e = 0; e < 8; ++e)
        v[e] = (short)bf16bits(W[(kh * 32 + kg * 8 + e) * 64 + nb * 16 + r]);
      wf[nb][kh] = v;
    }

  const f32x4 zero = {0.f, 0.f, 0.f, 0.f};
#pragma unroll
  for (int nb = 0; nb < 4; ++nb) {
    f32x4 acc = __builtin_amdgcn_mfma_f32_16x16x32_bf16(xa[0], wf[nb][0], zero, 0, 0, 0);
    acc = __builtin_amdgcn_mfma_f32_16x16x32_bf16(xa[1], wf[nb][1], acc, 0, 0, 0);
    float bb = bias[nb * 16 + r];
#pragma unroll
    for (int q = 0; q < 4; ++q) {
      float z = acc[q] + bb;
      // JAX default gelu (approximate=True, tanh form)
      float t = tanhf(0.7978845608028654f * (z + 0.044715f * z * z * z));
      float g = 0.5f * z * (1.0f + t);
      hb[(size_t)(row0 + kg * 4 + q) * 64 + nb * 16 + r] = bf16bits(g);
    }
  }
}

// ---------------- pair kernel ---------------------------------------------
// 1200 blocks = 300 pairs x (2 row-halves x 2 col-halves). Block =
// 256 A-rows x 256 B-rows. B half (256x64 bf16 = 32KB) staged once to
// LDS (XOR-swizzled, pre-swizzled global source + swizzled read). Wave =
// 64 A-rows (a[4][2] regs) x 256 cols (16 cn). Compiler-scheduled body.
__global__ __launch_bounds__(256) void pair_kernel(
    const u16* __restrict__ hb, float* __restrict__ part) {
  __shared__ char smem[32768];

  int idx = blockIdx.x;
  int p = idx >> 2;
  int tile = idx & 3;
  int rh = tile >> 1;          // row half of A (256 rows)
  int ch = tile & 1;           // col half of B (256 rows)
  // decode triangular index p -> (i,j), i<=j
  int i = 0, rem = p;
  while (rem >= 24 - i) { rem -= 24 - i; ++i; }
  int j = i + rem;

  const u16* Ap = hb + (size_t)i * 512 * 64;
  const char* Bbytes =
      (const char*)(hb + (size_t)j * 512 * 64) + (size_t)ch * 256 * 128;

  int wid = threadIdx.x >> 6;
  int lane = threadIdx.x & 63;
  int r = lane & 15;        // row-in-fragment
  int kg = lane >> 4;       // k-group (8 contiguous bf16 = 16B)
  int row0 = rh * 256 + wid * 64;

  // A fragments: 64 rows, K=64 (4 rm x 2 k-halves) — one-time L2 loads.
  bf16x8 a[4][2];
#pragma unroll
  for (int rm = 0; rm < 4; ++rm)
#pragma unroll
    for (int kf = 0; kf < 2; ++kf)
      a[rm][kf] = *reinterpret_cast<const bf16x8*>(
          Ap + (size_t)(row0 + rm * 16 + r) * 64 + kf * 32 + kg * 8);

  // Stage B half: 32KB = 4 waves x 8 calls x 1KB. LDS dest linear;
  // global source pre-swizzled with the involution the reads use.
#pragma unroll
  for (int c = 0; c < 8; ++c) {
    int obase = (wid * 8 + c) * 1024;
    int o = obase + lane * 16;
    int src = o ^ (((o >> 7) & 7) << 4);
    __builtin_amdgcn_global_load_lds(
        (const __attribute__((address_space(1))) void*)(Bbytes + src),
        (__attribute__((address_space(3))) void*)(smem + obase), 16, 0, 0);
  }

  // Per-lane LDS read offsets (swizzle bits depend only on lane).
  int sw = (r & 7) << 4;
  int off0 = r * 128 + ((kg * 16) ^ sw);
  int off1 = r * 128 + ((64 + kg * 16) ^ sw);

  __syncthreads();

  float s0 = 0.f, s1 = 0.f, s2 = 0.f, s3 = 0.f;
  const f32x4 zero = {0.f, 0.f, 0.f, 0.f};

#pragma unroll
  for (int cn = 0; cn < 16; ++cn) {
    const char* bp = smem + cn * 2048;
    bf16x8 b0 = *reinterpret_cast<const bf16x8*>(bp + off0);
    bf16x8 b1 = *reinterpret_cast<const bf16x8*>(bp + off1);
#pragma unroll
    for (int rm = 0; rm < 4; ++rm) {
      f32x4 acc = __builtin_amdgcn_mfma_f32_16x16x32_bf16(a[rm][0], b0, zero, 0, 0, 0);
      acc = __builtin_amdgcn_mfma_f32_16x16x32_bf16(a[rm][1], b1, acc, 0, 0, 0);
      s0 += fast_exp(acc[0]);
      s1 += fast_exp(acc[1]);
      s2 += fast_exp(acc[2]);
      s3 += fast_exp(acc[3]);
    }
  }
  float sum = (s0 + s1) + (s2 + s3);
#pragma unroll
  for (int off = 32; off >= 1; off >>= 1) sum += __shfl_xor(sum, off, 64);
  if (lane == 0) part[idx * 4 + wid] = sum;
}

// ---------------- finalize: sum 16 partials per pair, log, mirror ---------
__global__ void finish_kernel(const float* __restrict__ part,
                              float* __restrict__ out) {
  int t = threadIdx.x + blockIdx.x * blockDim.x;
  if (t >= 576) return;
  int i = t / 24, j = t % 24;
  int ii = i < j ? i : j, jj = i < j ? j : i;
  int p = ii * 24 - ii * (ii - 1) / 2 + (jj - ii);
  const f32x4* pv = reinterpret_cast<const f32x4*>(part + p * 16);
  float s = 0.f;
#pragma unroll
  for (int q = 0; q < 4; ++q) {
    f32x4 v = pv[q];
    s += (v[0] + v[1]) + (v[2] + v[3]);
  }
  out[t] = logf(s);
}

extern "C" void kernel_launch(void* const* d_in, const int* in_sizes, int n_in,
                              void* d_out, int out_size, void* d_ws,
                              size_t ws_size, hipStream_t stream) {
  const float* x = (const float*)d_in[0];
  const float* W = (const float*)d_in[1];
  const float* bias = (const float*)d_in[2];
  float* out = (float*)d_out;

  u16* hb = (u16*)d_ws;                      // 12288*64 bf16 = 1.50 MiB
  float* part = (float*)(hb + 12288 * 64);   // 1200 * 4 = 4800 f32

  encode_kernel<<<192, 256, 0, stream>>>(x, W, bias, hb);
  pair_kernel<<<1200, 256, 0, stream>>>(hb, part);
  finish_kernel<<<9, 64, 0, stream>>>(part, out);
}

// Round 15
// 25.484 us; speedup vs baseline: 5.1088x; 1.0287x over previous
//
#include <hip/hip_runtime.h>
#include <hip/hip_bf16.h>

// Problem: B=24, L=512, D=64, H=64
//   h = gelu(x @ W + b); S = h_i h_j^T per pair; scores = logsumexp(S).
// 300 unique (i<=j) pairs, mirrored at the end.
//
// R15 = R14 (26.2us best) with the pair inner loop moved from
// mfma_f32_16x16x32 to mfma_f32_32x32x16 (2382 vs 2075 TF measured;
// half the MFMA instruction count, 32-elem exp bursts). MFMA-issue was
// the largest pipe load (~5.2us/CU of pair's ~12.5us). A/B fragments
// use the mirror-identical lane->(row, 8-contig-k) mapping; the whole-
// tile SUM makes C/D placement irrelevant. Everything else unchanged:
// Schraudolph e^x with folded log2e, single hb array, 32KB swizzled
// LDS staging, 3 dispatches, slot-writes, no atomics/memset.

typedef unsigned short u16;
typedef __attribute__((ext_vector_type(8))) short bf16x8;
typedef __attribute__((ext_vector_type(4))) float f32x4;
typedef __attribute__((ext_vector_type(16))) float f32x16;

static __device__ __forceinline__ u16 bf16bits(float f) {
  __hip_bfloat16 h = __float2bfloat16(f);
  return *reinterpret_cast<u16*>(&h);
}

// Schraudolph fast e^x (log2e folded into the multiplier):
// e^x ~= as_float((int)(x*log2e*2^23 + (127*2^23 - 254615))).
// Valid |x| < 87; rel err <= 3.04%  ->  <=0.03 absolute on log-scores.
static __device__ __forceinline__ float fast_exp(float x) {
  int i = (int)fmaf(x, 12102203.0f, 1065098601.0f);
  return __int_as_float(i);
}

// ---------------- encoder: h = gelu(x@W+b) via MFMA (unchanged) -----------
__global__ __launch_bounds__(256) void encode_kernel(
    const float* __restrict__ x, const float* __restrict__ W,
    const float* __restrict__ bias, u16* __restrict__ hb) {
  int lane = threadIdx.x & 63;
  int wid = threadIdx.x >> 6;
  int row0 = (blockIdx.x * 4 + wid) * 16;      // 12288 rows / 16 = 768 waves
  int r = lane & 15;
  int kg = lane >> 4;

  bf16x8 xa[2];
#pragma unroll
  for (int kh = 0; kh < 2; ++kh) {
    const float* xp = x + (size_t)(row0 + r) * 64 + kh * 32 + kg * 8;
    bf16x8 v;
#pragma unroll
    for (int e = 0; e < 8; ++e) v[e] = (short)bf16bits(xp[e]);
    xa[kh] = v;
  }

  bf16x8 wf[4][2];
#pragma unroll
  for (int nb = 0; nb < 4; ++nb)
#pragma unroll
    for (int kh = 0; kh < 2; ++kh) {
      bf16x8 v;
#pragma unroll
      for (int e = 0; e < 8; ++e)
        v[e] = (short)bf16bits(W[(kh * 32 + kg * 8 + e) * 64 + nb * 16 + r]);
      wf[nb][kh] = v;
    }

  const f32x4 zero = {0.f, 0.f, 0.f, 0.f};
#pragma unroll
  for (int nb = 0; nb < 4; ++nb) {
    f32x4 acc = __builtin_amdgcn_mfma_f32_16x16x32_bf16(xa[0], wf[nb][0], zero, 0, 0, 0);
    acc = __builtin_amdgcn_mfma_f32_16x16x32_bf16(xa[1], wf[nb][1], acc, 0, 0, 0);
    float bb = bias[nb * 16 + r];
#pragma unroll
    for (int q = 0; q < 4; ++q) {
      float z = acc[q] + bb;
      // JAX default gelu (approximate=True, tanh form)
      float t = tanhf(0.7978845608028654f * (z + 0.044715f * z * z * z));
      float g = 0.5f * z * (1.0f + t);
      hb[(size_t)(row0 + kg * 4 + q) * 64 + nb * 16 + r] = bf16bits(g);
    }
  }
}

// ---------------- pair kernel (32x32x16 MFMA) ------------------------------
// 1200 blocks = 300 pairs x (2 row-halves x 2 col-halves). Block =
// 256 A-rows x 256 B-rows; B half (32KB) staged once to LDS (swizzled).
// Wave = 64 A-rows (2 row-tiles of 32, a[2][4] frags) x 256 cols
// (8 cn of 32). Per cn: 4 ds_read_b128 + 2x (4-chain MFMA + 16 exps).
__global__ __launch_bounds__(256) void pair_kernel(
    const u16* __restrict__ hb, float* __restrict__ part) {
  __shared__ char smem[32768];

  int idx = blockIdx.x;
  int p = idx >> 2;
  int tile = idx & 3;
  int rh = tile >> 1;          // row half of A (256 rows)
  int ch = tile & 1;           // col half of B (256 rows)
  // decode triangular index p -> (i,j), i<=j
  int i = 0, rem = p;
  while (rem >= 24 - i) { rem -= 24 - i; ++i; }
  int j = i + rem;

  const u16* Ap = hb + (size_t)i * 512 * 64;
  const char* Bbytes =
      (const char*)(hb + (size_t)j * 512 * 64) + (size_t)ch * 256 * 128;

  int wid = threadIdx.x >> 6;
  int lane = threadIdx.x & 63;
  int r32 = lane & 31;      // row-in-32-fragment
  int kg2 = lane >> 5;      // k-group (8 contiguous bf16 = 16B), K=16/mfma
  int row0 = rh * 256 + wid * 64;

  // A fragments: 64 rows = 2 tiles of 32, K=64 = 4 kf slices of 16.
  // lane holds A[row = t*32 + r32][k = kf*16 + kg2*8 + e].
  bf16x8 a[2][4];
#pragma unroll
  for (int t = 0; t < 2; ++t)
#pragma unroll
    for (int kf = 0; kf < 4; ++kf)
      a[t][kf] = *reinterpret_cast<const bf16x8*>(
          Ap + (size_t)(row0 + t * 32 + r32) * 64 + kf * 16 + kg2 * 8);

  // Stage B half: 32KB = 4 waves x 8 calls x 1KB. LDS dest linear;
  // global source pre-swizzled with the involution the reads use.
#pragma unroll
  for (int c = 0; c < 8; ++c) {
    int obase = (wid * 8 + c) * 1024;
    int o = obase + lane * 16;
    int src = o ^ (((o >> 7) & 7) << 4);
    __builtin_amdgcn_global_load_lds(
        (const __attribute__((address_space(1))) void*)(Bbytes + src),
        (__attribute__((address_space(3))) void*)(smem + obase), 16, 0, 0);
  }

  // Per-lane LDS read offsets (swizzle bits depend only on lane).
  // B row (= S column) cn*32 + r32; byte col (kf*32 + kg2*16) ^ swz.
  int swz = (r32 & 7) << 4;
  int boff[4];
#pragma unroll
  for (int kf = 0; kf < 4; ++kf)
    boff[kf] = r32 * 128 + ((kf * 32 + kg2 * 16) ^ swz);

  __syncthreads();

  float s0 = 0.f, s1 = 0.f, s2 = 0.f, s3 = 0.f;
  const f32x16 zero16 = {0.f, 0.f, 0.f, 0.f, 0.f, 0.f, 0.f, 0.f,
                         0.f, 0.f, 0.f, 0.f, 0.f, 0.f, 0.f, 0.f};

#pragma unroll
  for (int cn = 0; cn < 8; ++cn) {
    const char* bp = smem + cn * 4096;   // 32 rows x 128 B per cn
    bf16x8 b0 = *reinterpret_cast<const bf16x8*>(bp + boff[0]);
    bf16x8 b1 = *reinterpret_cast<const bf16x8*>(bp + boff[1]);
    bf16x8 b2 = *reinterpret_cast<const bf16x8*>(bp + boff[2]);
    bf16x8 b3 = *reinterpret_cast<const bf16x8*>(bp + boff[3]);
#pragma unroll
    for (int t = 0; t < 2; ++t) {
      f32x16 acc = __builtin_amdgcn_mfma_f32_32x32x16_bf16(a[t][0], b0, zero16, 0, 0, 0);
      acc = __builtin_amdgcn_mfma_f32_32x32x16_bf16(a[t][1], b1, acc, 0, 0, 0);
      acc = __builtin_amdgcn_mfma_f32_32x32x16_bf16(a[t][2], b2, acc, 0, 0, 0);
      acc = __builtin_amdgcn_mfma_f32_32x32x16_bf16(a[t][3], b3, acc, 0, 0, 0);
#pragma unroll
      for (int q = 0; q < 16; q += 4) {
        s0 += fast_exp(acc[q + 0]);
        s1 += fast_exp(acc[q + 1]);
        s2 += fast_exp(acc[q + 2]);
        s3 += fast_exp(acc[q + 3]);
      }
    }
  }
  float sum = (s0 + s1) + (s2 + s3);
#pragma unroll
  for (int off = 32; off >= 1; off >>= 1) sum += __shfl_xor(sum, off, 64);
  if (lane == 0) part[idx * 4 + wid] = sum;
}

// ---------------- finalize: sum 16 partials per pair, log, mirror ---------
__global__ void finish_kernel(const float* __restrict__ part,
                              float* __restrict__ out) {
  int t = threadIdx.x + blockIdx.x * blockDim.x;
  if (t >= 576) return;
  int i = t / 24, j = t % 24;
  int ii = i < j ? i : j, jj = i < j ? j : i;
  int p = ii * 24 - ii * (ii - 1) / 2 + (jj - ii);
  const f32x4* pv = reinterpret_cast<const f32x4*>(part + p * 16);
  float s = 0.f;
#pragma unroll
  for (int q = 0; q < 4; ++q) {
    f32x4 v = pv[q];
    s += (v[0] + v[1]) + (v[2] + v[3]);
  }
  out[t] = logf(s);
}

extern "C" void kernel_launch(void* const* d_in, const int* in_sizes, int n_in,
                              void* d_out, int out_size, void* d_ws,
                              size_t ws_size, hipStream_t stream) {
  const float* x = (const float*)d_in[0];
  const float* W = (const float*)d_in[1];
  const float* bias = (const float*)d_in[2];
  float* out = (float*)d_out;

  u16* hb = (u16*)d_ws;                      // 12288*64 bf16 = 1.50 MiB
  float* part = (float*)(hb + 12288 * 64);   // 1200 * 4 = 4800 f32

  encode_kernel<<<192, 256, 0, stream>>>(x, W, bias, hb);
  pair_kernel<<<1200, 256, 0, stream>>>(hb, part);
  finish_kernel<<<9, 64, 0, stream>>>(part, out);
}